// Round 14
// baseline (172.142 us; speedup 1.0000x reference)
//
#include <hip/hip_runtime.h>
#include <hip/hip_bf16.h>
#include <math.h>

// Problem constants (PoseMixtureVAE)
#define N_BATCH 4096
#define FRAME   267
#define LATENT  32
#define HIDDEN  256
#define GATE_H  64
#define EXPERTS 6
// Kpads: [x|c]=534->544 (17 ksteps), [x|h]=523->544 (17), [z|c]=299->320 (10),
//        [z|h]=288 (9 exactly), gate hidden 64 (2)

typedef __hip_bfloat16 bf16;
typedef __bf16  bf16x8 __attribute__((ext_vector_type(8)));
typedef float   f32x4  __attribute__((ext_vector_type(4)));

__device__ __forceinline__ float eluf(float v) { return (v > 0.f) ? v : (expf(v) - 1.f); }

#define MFMA(a, b, p) __builtin_amdgcn_mfma_f32_16x16x32_bf16((a), (b), (p), 0, 0, 0)

struct WEnt { const float* src; bf16* dst; int K, M, Mtot, mOff, Ksteps, Mtiles, cum; };
struct WTab { WEnt e[10]; int total; };

// ---------------------------------------------------------------------------
// prep: weight repack (one 32x32 tile unit per block) + biasCat.
// ---------------------------------------------------------------------------
__global__ __launch_bounds__(256) void prep_kernel(
    const float* __restrict__ bmu, const float* __restrict__ blv,
    float* __restrict__ biasCat, WTab tab)
{
    const int tid = threadIdx.x, bid = blockIdx.x;
    if (bid == 0 && tid < 64)
        biasCat[tid] = (tid < 32) ? bmu[tid] : blv[tid - 32];

    __shared__ float tbuf[32][33];
    int i = 0;
    while (i < 9 && bid >= tab.e[i + 1].cum) ++i;
    const WEnt en = tab.e[i];
    const int t = bid - en.cum;
    const int perE = en.Ksteps * en.Mtiles;
    const int e = t / perE;
    const int rr = t - e * perE;
    const int mt = rr / en.Ksteps;
    const int ks = rr - mt * en.Ksteps;
    const int tx = tid & 31, ty = tid >> 5;
    const float* src = en.src + (size_t)e * en.K * en.M;
    #pragma unroll
    for (int i0 = 0; i0 < 32; i0 += 8) {
        const int k = ks * 32 + i0 + ty, m = mt * 32 + tx;
        tbuf[i0 + ty][tx] = (k < en.K && m < en.M) ? src[(size_t)k * en.M + m] : 0.f;
    }
    __syncthreads();
    bf16* dst = en.dst + ((size_t)(e * en.Ksteps + ks) * en.Mtot + en.mOff + mt * 32) * 32;
    #pragma unroll
    for (int i0 = 0; i0 < 32; i0 += 8)
        dst[(size_t)(i0 + ty) * 32 + tx] = __float2bfloat16(tbuf[tx][i0 + ty]);
}

// ---------------------------------------------------------------------------
// fused: ENTIRE network, 16 rows/block, 256 blocks (1/CU), 1024 thr (16 waves).
// R14: all 256 blocks run phases in lockstep and read IDENTICAL weight lines
// simultaneously -> same-line serialization at each XCD's L2 port (delivered
// 13.4 TB/s = 39% of L2 ubench; TLP and pipeline depth both flat R7-R13).
// Fix: block-dependent ROTATION of the ks order in every weight-streaming
// phase (block b starts at ks = b % KS) -> blocks touch lines spread across
// the whole panel instead of one hot line. f32 accumulation reorder only.
// ---------------------------------------------------------------------------
__global__ __launch_bounds__(1024, 4) void fused_kernel(
    const float* __restrict__ x, const float* __restrict__ c,
    const float* __restrict__ eps,
    const bf16* __restrict__ We1, const float* __restrict__ eb1,
    const bf16* __restrict__ We2, const float* __restrict__ eb2,
    const bf16* __restrict__ Wml, const float* __restrict__ biasCat,
    const bf16* __restrict__ Wg0, const float* __restrict__ gb0,
    const bf16* __restrict__ Wg1, const float* __restrict__ gb1,
    const bf16* __restrict__ Wg2, const float* __restrict__ gb2,
    const bf16* __restrict__ W0, const float* __restrict__ b0,
    const bf16* __restrict__ W1, const float* __restrict__ b1,
    const bf16* __restrict__ W2, const float* __restrict__ b2,
    float* __restrict__ out_layer, float* __restrict__ out_mu,
    float* __restrict__ out_lv)
{
    __shared__ bf16  bufA[16 * 552];
    __shared__ bf16  bufB[16 * 552];
    __shared__ float sMLp[4][16 * 64];
    __shared__ bf16  sG1[16 * 72];
    __shared__ bf16  sG2[16 * 72];
    __shared__ float sLg[16 * 16];
    __shared__ float sCo[EXPERTS * 16];

    const int tid  = threadIdx.x;
    const int w    = tid >> 6, lane = tid & 63, ml = lane & 15, quad = lane >> 4;
    const int bid  = blockIdx.x;
    const int row0 = bid * 16;
    const int rot17 = bid % 17;          // de-phasing rotations
    const int rot10 = bid % 10;
    const int rot9  = bid % 9;

    // ---- Ph0: bufA = [x|c] bf16 (Kpad 544, zero 534..543). row = w. ----
    {
        const float* xr = x + (size_t)(row0 + w) * FRAME;
        const float* cr = c + (size_t)(row0 + w) * FRAME;
        #pragma unroll
        for (int j = 0; j < 9; ++j) {
            const int col = lane + j * 64;
            if (col < 544) {
                float v = 0.f;
                if (col < FRAME)          v = xr[col];
                else if (col < 2 * FRAME) v = cr[col - FRAME];
                bufA[w * 552 + col] = __float2bfloat16(v);
            }
        }
    }
    __syncthreads();

    // ---- Ph1: h1 = elu([x|c] @ We1 + eb1), M=256 (16 tiles); bufB=[x|h1] ----
    {
        const int col = 16 * w + ml;
        const bf16* wq = We1 + (size_t)col * 32 + quad * 8;   // ks-stride 8192
        f32x4 acc = (f32x4){0,0,0,0};
        #pragma unroll
        for (int i = 0; i < 17; ++i) {
            int ks = i + rot17; if (ks >= 17) ks -= 17;
            acc = MFMA(*(const bf16x8*)(bufA + ml * 552 + ks * 32 + quad * 8),
                       *(const bf16x8*)(wq + (size_t)ks * 8192), acc);
        }
        const float bv = eb1[col];
        #pragma unroll
        for (int rg = 0; rg < 4; ++rg)
            bufB[(quad * 4 + rg) * 552 + 267 + col] = __float2bfloat16(eluf(acc[rg] + bv));
        // copy x -> bufB[0..266] (row w); zero pad 523..543
        #pragma unroll
        for (int j = 0; j < 5; ++j) {
            const int cc = lane + j * 64;
            if (cc < 267) bufB[w * 552 + cc] = bufA[w * 552 + cc];
        }
        if (lane < 21) bufB[w * 552 + 523 + lane] = __float2bfloat16(0.f);
    }
    __syncthreads();

    // ---- Ph2: h2 = elu([x|h1] @ We2 + eb2) -> bufB in-place = [x|h2] ----
    {
        const int col = 16 * w + ml;
        const bf16* wq = We2 + (size_t)col * 32 + quad * 8;
        f32x4 acc = (f32x4){0,0,0,0};
        #pragma unroll
        for (int i = 0; i < 17; ++i) {
            int ks = i + rot17; if (ks >= 17) ks -= 17;
            acc = MFMA(*(const bf16x8*)(bufB + ml * 552 + ks * 32 + quad * 8),
                       *(const bf16x8*)(wq + (size_t)ks * 8192), acc);
        }
        __syncthreads();   // all reads of bufB done before overwrite
        const float bv = eb2[col];
        #pragma unroll
        for (int rg = 0; rg < 4; ++rg)
            bufB[(quad * 4 + rg) * 552 + 267 + col] = __float2bfloat16(eluf(acc[rg] + bv));
    }
    __syncthreads();

    // ---- Ph3: mu|lv partial-K: wave w -> col tile (w&3), k-group (w>>2) ----
    {
        const int t = w & 3, kg = w >> 2;
        const int col = 16 * t + ml;
        const int k0 = kg * 4, k1 = (kg == 3) ? 17 : kg * 4 + 4;
        const bf16* wq = Wml + (size_t)col * 32 + quad * 8;   // ks-stride 2048
        f32x4 p = (f32x4){0,0,0,0};
        #pragma unroll
        for (int u = 0; u < 5; ++u) {
            const int ks = k0 + u;
            if (ks < k1)
                p = MFMA(*(const bf16x8*)(bufB + ml * 552 + ks * 32 + quad * 8),
                         *(const bf16x8*)(wq + (size_t)ks * 2048), p);
        }
        #pragma unroll
        for (int rg = 0; rg < 4; ++rg)
            sMLp[kg][(quad * 4 + rg) * 64 + col] = p[rg];
    }
    __syncthreads();

    // ---- Ph3b: z; bufB = [z|c] (Kpad 320); bufA[0..31] = z ----
    if (tid < 512) {
        const int r = tid >> 5, l = tid & 31;
        const float m  = sMLp[0][r * 64 + l] + sMLp[1][r * 64 + l]
                       + sMLp[2][r * 64 + l] + sMLp[3][r * 64 + l] + biasCat[l];
        const float lv = sMLp[0][r * 64 + 32 + l] + sMLp[1][r * 64 + 32 + l]
                       + sMLp[2][r * 64 + 32 + l] + sMLp[3][r * 64 + 32 + l] + biasCat[32 + l];
        const int gi = (row0 + r) * LATENT + l;
        out_mu[gi] = m; out_lv[gi] = lv;
        const bf16 zb = __float2bfloat16(m + eps[gi] * expf(0.5f * lv));
        bufA[r * 552 + l] = zb;       // prefix of [z|dh1]
        bufB[r * 552 + l] = zb;       // prefix of [z|c]
        #pragma unroll
        for (int j = 0; j < 9; ++j) {
            const int col = 32 + l + j * 32;          // 32..319
            bf16 v = __float2bfloat16(0.f);
            if (col < 299) v = bufA[r * 552 + 267 + (col - 32)];   // c
            bufB[r * 552 + col] = v;
        }
    }
    __syncthreads();

    // ---- Ph5: MoE layer 0, ks-outer (rotated); gate overlapped ----
    {
        const int col = 16 * w + ml;
        const bf16* wq = W0 + (size_t)col * 32 + quad * 8;    // (e*10+ks)-stride 8192
        f32x4 pe0 = (f32x4){0,0,0,0}, pe1 = (f32x4){0,0,0,0}, pe2 = (f32x4){0,0,0,0};
        f32x4 pe3 = (f32x4){0,0,0,0}, pe4 = (f32x4){0,0,0,0}, pe5 = (f32x4){0,0,0,0};

        // chunk A: gate g1 (waves 0-3) + experts 0-2 (ks-outer rotated)
        if (w < 4) {
            const int gc = 16 * w + ml;
            const bf16* gq = Wg0 + (size_t)gc * 32 + quad * 8;   // ks-stride 2048
            f32x4 p = (f32x4){0,0,0,0};
            #pragma unroll
            for (int ks = 0; ks < 10; ++ks)
                p = MFMA(*(const bf16x8*)(bufB + ml * 552 + ks * 32 + quad * 8),
                         *(const bf16x8*)(gq + (size_t)ks * 2048), p);
            const float bv = gb0[gc];
            #pragma unroll
            for (int rg = 0; rg < 4; ++rg)
                sG1[(quad * 4 + rg) * 72 + gc] = __float2bfloat16(eluf(p[rg] + bv));
        }
        #pragma unroll
        for (int i = 0; i < 10; ++i) {
            int ks = i + rot10; if (ks >= 10) ks -= 10;
            const bf16x8 a = *(const bf16x8*)(bufB + ml * 552 + ks * 32 + quad * 8);
            pe0 = MFMA(a, *(const bf16x8*)(wq + (size_t)(0 * 10 + ks) * 8192), pe0);
            pe1 = MFMA(a, *(const bf16x8*)(wq + (size_t)(1 * 10 + ks) * 8192), pe1);
            pe2 = MFMA(a, *(const bf16x8*)(wq + (size_t)(2 * 10 + ks) * 8192), pe2);
        }
        __syncthreads();

        // chunk B: gate g2+logits+softmax (wave 0) + experts 3-5 (rotated)
        if (w == 0) {
            #pragma unroll
            for (int t = 0; t < 4; ++t) {
                const int gc = 16 * t + ml;
                const bf16* gq = Wg1 + (size_t)gc * 32 + quad * 8;
                f32x4 p = (f32x4){0,0,0,0};
                #pragma unroll
                for (int ks = 0; ks < 2; ++ks)
                    p = MFMA(*(const bf16x8*)(sG1 + ml * 72 + ks * 32 + quad * 8),
                             *(const bf16x8*)(gq + (size_t)ks * 2048), p);
                const float bv = gb1[gc];
                #pragma unroll
                for (int rg = 0; rg < 4; ++rg)
                    sG2[(quad * 4 + rg) * 72 + gc] = __float2bfloat16(eluf(p[rg] + bv));
            }
            {
                const bf16* gq = Wg2 + (size_t)ml * 32 + quad * 8;   // ks-stride 1024
                f32x4 p = (f32x4){0,0,0,0};
                #pragma unroll
                for (int ks = 0; ks < 2; ++ks)
                    p = MFMA(*(const bf16x8*)(sG2 + ml * 72 + ks * 32 + quad * 8),
                             *(const bf16x8*)(gq + (size_t)ks * 1024), p);
                const float bv = (ml < EXPERTS) ? gb2[ml] : 0.f;
                #pragma unroll
                for (int rg = 0; rg < 4; ++rg)
                    sLg[(quad * 4 + rg) * 16 + ml] = p[rg] + bv;
            }
            if (lane < 16) {   // softmax (same wave -> sLg visible via lgkmcnt)
                float v[EXPERTS];
                float m = -1e30f;
                #pragma unroll
                for (int i = 0; i < EXPERTS; ++i) { v[i] = sLg[lane * 16 + i]; m = fmaxf(m, v[i]); }
                float s = 0.f;
                #pragma unroll
                for (int i = 0; i < EXPERTS; ++i) { v[i] = expf(v[i] - m); s += v[i]; }
                const float inv = 1.f / s;
                #pragma unroll
                for (int i = 0; i < EXPERTS; ++i) sCo[i * 16 + lane] = v[i] * inv;
            }
        }
        #pragma unroll
        for (int i = 0; i < 10; ++i) {
            int ks = i + rot10; if (ks >= 10) ks -= 10;
            const bf16x8 a = *(const bf16x8*)(bufB + ml * 552 + ks * 32 + quad * 8);
            pe3 = MFMA(a, *(const bf16x8*)(wq + (size_t)(3 * 10 + ks) * 8192), pe3);
            pe4 = MFMA(a, *(const bf16x8*)(wq + (size_t)(4 * 10 + ks) * 8192), pe4);
            pe5 = MFMA(a, *(const bf16x8*)(wq + (size_t)(5 * 10 + ks) * 8192), pe5);
        }
        __syncthreads();   // sCo ready + all partials done

        f32x4 acc = (f32x4){0,0,0,0};
        auto blend = [&](const f32x4& p, int e) {
            const float bv = b0[e * 256 + col];
            #pragma unroll
            for (int rg = 0; rg < 4; ++rg)
                acc[rg] += sCo[e * 16 + quad * 4 + rg] * (p[rg] + bv);
        };
        blend(pe0, 0); blend(pe1, 1); blend(pe2, 2);
        blend(pe3, 3); blend(pe4, 4); blend(pe5, 5);
        #pragma unroll
        for (int rg = 0; rg < 4; ++rg)
            bufA[(quad * 4 + rg) * 552 + 32 + col] = __float2bfloat16(eluf(acc[rg]));
    }
    __syncthreads();

    // ---- Ph6: dh2 = elu(moe([z|dh1], W1, b1)), ks-outer (rotated) ----
    {
        const int col = 16 * w + ml;
        const bf16* wq = W1 + (size_t)col * 32 + quad * 8;    // (e*9+ks)-stride 8192
        f32x4 pe0 = (f32x4){0,0,0,0}, pe1 = (f32x4){0,0,0,0}, pe2 = (f32x4){0,0,0,0};
        f32x4 pe3 = (f32x4){0,0,0,0}, pe4 = (f32x4){0,0,0,0}, pe5 = (f32x4){0,0,0,0};
        #pragma unroll
        for (int i = 0; i < 9; ++i) {
            int ks = i + rot9; if (ks >= 9) ks -= 9;
            const bf16x8 a = *(const bf16x8*)(bufA + ml * 552 + ks * 32 + quad * 8);
            pe0 = MFMA(a, *(const bf16x8*)(wq + (size_t)(0 * 9 + ks) * 8192), pe0);
            pe1 = MFMA(a, *(const bf16x8*)(wq + (size_t)(1 * 9 + ks) * 8192), pe1);
            pe2 = MFMA(a, *(const bf16x8*)(wq + (size_t)(2 * 9 + ks) * 8192), pe2);
            pe3 = MFMA(a, *(const bf16x8*)(wq + (size_t)(3 * 9 + ks) * 8192), pe3);
            pe4 = MFMA(a, *(const bf16x8*)(wq + (size_t)(4 * 9 + ks) * 8192), pe4);
            pe5 = MFMA(a, *(const bf16x8*)(wq + (size_t)(5 * 9 + ks) * 8192), pe5);
        }
        f32x4 acc = (f32x4){0,0,0,0};
        auto blend = [&](const f32x4& p, int e) {
            const float bv = b1[e * 256 + col];
            #pragma unroll
            for (int rg = 0; rg < 4; ++rg)
                acc[rg] += sCo[e * 16 + quad * 4 + rg] * (p[rg] + bv);
        };
        blend(pe0, 0); blend(pe1, 1); blend(pe2, 2);
        blend(pe3, 3); blend(pe4, 4); blend(pe5, 5);
        // writes to bufB; its last reads were before the Ph5-end barrier
        #pragma unroll
        for (int rg = 0; rg < 4; ++rg)
            bufB[(quad * 4 + rg) * 552 + 32 + col] = __float2bfloat16(eluf(acc[rg]));
    }
    __syncthreads();

    // ---- Ph7: out = moe([z|dh2], W2, b2), M=267 (17 tiles), rotated ----
    {
        for (int t = w; t < 17; t += 16) {
            const int col = 16 * t + ml;
            const bf16* wq = W2 + (size_t)col * 32 + quad * 8;   // (e*9+ks)-stride 10240
            f32x4 pe0 = (f32x4){0,0,0,0}, pe1 = (f32x4){0,0,0,0}, pe2 = (f32x4){0,0,0,0};
            f32x4 pe3 = (f32x4){0,0,0,0}, pe4 = (f32x4){0,0,0,0}, pe5 = (f32x4){0,0,0,0};
            #pragma unroll
            for (int i = 0; i < 9; ++i) {
                int ks = i + rot9; if (ks >= 9) ks -= 9;
                const bf16x8 a = *(const bf16x8*)(bufB + ml * 552 + ks * 32 + quad * 8);
                pe0 = MFMA(a, *(const bf16x8*)(wq + (size_t)(0 * 9 + ks) * 10240), pe0);
                pe1 = MFMA(a, *(const bf16x8*)(wq + (size_t)(1 * 9 + ks) * 10240), pe1);
                pe2 = MFMA(a, *(const bf16x8*)(wq + (size_t)(2 * 9 + ks) * 10240), pe2);
                pe3 = MFMA(a, *(const bf16x8*)(wq + (size_t)(3 * 9 + ks) * 10240), pe3);
                pe4 = MFMA(a, *(const bf16x8*)(wq + (size_t)(4 * 9 + ks) * 10240), pe4);
                pe5 = MFMA(a, *(const bf16x8*)(wq + (size_t)(5 * 9 + ks) * 10240), pe5);
            }
            f32x4 acc = (f32x4){0,0,0,0};
            auto blend = [&](const f32x4& p, int e) {
                const float bv = (col < FRAME) ? b2[e * FRAME + col] : 0.f;
                #pragma unroll
                for (int rg = 0; rg < 4; ++rg)
                    acc[rg] += sCo[e * 16 + quad * 4 + rg] * (p[rg] + bv);
            };
            blend(pe0, 0); blend(pe1, 1); blend(pe2, 2);
            blend(pe3, 3); blend(pe4, 4); blend(pe5, 5);
            if (col < FRAME) {
                #pragma unroll
                for (int rg = 0; rg < 4; ++rg)
                    out_layer[(size_t)(row0 + quad * 4 + rg) * FRAME + col] = acc[rg];
            }
        }
    }
}

// ---------------------------------------------------------------------------
extern "C" void kernel_launch(void* const* d_in, const int* in_sizes, int n_in,
                              void* d_out, int out_size, void* d_ws, size_t ws_size,
                              hipStream_t stream) {
    const float* x       = (const float*)d_in[0];
    const float* c       = (const float*)d_in[1];
    const float* eps     = (const float*)d_in[2];
    const float* enc_w1  = (const float*)d_in[3];
    const float* enc_b1  = (const float*)d_in[4];
    const float* enc_w2  = (const float*)d_in[5];
    const float* enc_b2  = (const float*)d_in[6];
    const float* enc_wmu = (const float*)d_in[7];
    const float* enc_bmu = (const float*)d_in[8];
    const float* enc_wlv = (const float*)d_in[9];
    const float* enc_blv = (const float*)d_in[10];
    const float* g_w0    = (const float*)d_in[11];
    const float* g_b0    = (const float*)d_in[12];
    const float* g_w1    = (const float*)d_in[13];
    const float* g_b1    = (const float*)d_in[14];
    const float* g_w2    = (const float*)d_in[15];
    const float* g_b2    = (const float*)d_in[16];
    const float* w0      = (const float*)d_in[17];
    const float* b0      = (const float*)d_in[18];
    const float* w1      = (const float*)d_in[19];
    const float* b1      = (const float*)d_in[20];
    const float* w2      = (const float*)d_in[21];
    const float* b2      = (const float*)d_in[22];

    // output (f32): [layer (4096x267) | mu (4096x32) | logvar (4096x32)]
    float* out_layer = (float*)d_out;
    float* out_mu    = out_layer + (size_t)N_BATCH * FRAME;
    float* out_lv    = out_mu    + (size_t)N_BATCH * LATENT;

    // ---- workspace layout (16B-aligned): biasCat + repacked weights only ----
    char* p = (char*)d_ws;
    float* biasCat = (float*)p;  p += 64 * 4;
    bf16* Wt_e1 = (bf16*)p;      p += (size_t)17 * 256 * 32 * 2;
    bf16* Wt_e2 = (bf16*)p;      p += (size_t)17 * 256 * 32 * 2;
    bf16* Wt_ml = (bf16*)p;      p += (size_t)17 * 64 * 32 * 2;
    bf16* Wt_g0 = (bf16*)p;      p += (size_t)10 * 64 * 32 * 2;
    bf16* Wt_g1 = (bf16*)p;      p += (size_t)2 * 64 * 32 * 2;
    bf16* Wt_g2 = (bf16*)p;      p += (size_t)2 * 32 * 32 * 2;
    bf16* Wt_w0 = (bf16*)p;      p += (size_t)EXPERTS * 10 * 256 * 32 * 2;
    bf16* Wt_w1 = (bf16*)p;      p += (size_t)EXPERTS * 9 * 256 * 32 * 2;
    bf16* Wt_w2 = (bf16*)p;      p += (size_t)EXPERTS * 9 * 320 * 32 * 2;

    WTab tab;
    int cum = 0, n = 0;
    auto add = [&](const float* src, bf16* dst, int K, int M, int Mtot, int mOff, int E) {
        int Ksteps;
        if (K == 534 || K == 523) Ksteps = 17;
        else if (K == 299) Ksteps = 10;
        else if (K == 288) Ksteps = 9;
        else Ksteps = 2;   // K=64
        const int Mtiles = (M + 31) / 32;
        tab.e[n] = {src, dst, K, M, Mtot, mOff, Ksteps, Mtiles, cum};
        cum += E * Ksteps * Mtiles;
        ++n;
    };
    add(enc_w1,  Wt_e1, 534, 256, 256, 0, 1);
    add(enc_w2,  Wt_e2, 523, 256, 256, 0, 1);
    add(enc_wmu, Wt_ml, 523, 32, 64, 0, 1);
    add(enc_wlv, Wt_ml, 523, 32, 64, 32, 1);
    add(g_w0,    Wt_g0, 299, 64, 64, 0, 1);
    add(g_w1,    Wt_g1, 64, 64, 64, 0, 1);
    add(g_w2,    Wt_g2, 64, 6, 32, 0, 1);
    add(w0,      Wt_w0, 299, 256, 256, 0, EXPERTS);
    add(w1,      Wt_w1, 288, 256, 256, 0, EXPERTS);
    add(w2,      Wt_w2, 288, 267, 320, 0, EXPERTS);
    tab.total = cum;

    // 0) prep: weight repack (cum blocks) + biasCat
    prep_kernel<<<dim3(cum), dim3(256), 0, stream>>>(enc_bmu, enc_blv, biasCat, tab);

    // 1) fully fused network: 256 blocks x 1024 threads (1 block/CU, 16 waves)
    fused_kernel<<<dim3(N_BATCH / 16), dim3(1024), 0, stream>>>(
        x, c, eps,
        Wt_e1, enc_b1, Wt_e2, enc_b2, Wt_ml, biasCat,
        Wt_g0, g_b0, Wt_g1, g_b1, Wt_g2, g_b2,
        Wt_w0, b0, Wt_w1, b1, Wt_w2, b2,
        out_layer, out_mu, out_lv);
}